// Round 1
// baseline (364.201 us; speedup 1.0000x reference)
//
#include <hip/hip_runtime.h>

// Problem constants (from reference setup_inputs)
#define BD  32                 // batch
#define DD  256                // embedding dim
#define HWD 1024               // H*W = 32*32
#define NN  (BD*HWD)           // 32768 vectors
#define KK  1024               // codebook entries
#define ZQ_SIZE (NN*DD)        // 8388608
#define IDX_OFF ZQ_SIZE
#define LOSS_OFF (ZQ_SIZE + NN)

// ---------------------------------------------------------------------------
// Kernel A: codebook row norms ||c_k||^2 -> scratch (start of z_q region,
// overwritten later by kernel C).
__global__ __launch_bounds__(256)
void vq_cnorm_kernel(const float* __restrict__ cb, float* __restrict__ cnorm_out) {
    int k = blockIdx.x * 256 + threadIdx.x;   // grid = 4 blocks -> k in [0,1024)
    const float4* row = (const float4*)(cb + (size_t)k * DD);
    float s = 0.f;
#pragma unroll
    for (int i = 0; i < DD / 4; ++i) {
        float4 v = row[i];
        s = fmaf(v.x, v.x, s);
        s = fmaf(v.y, v.y, s);
        s = fmaf(v.z, v.z, s);
        s = fmaf(v.w, v.w, s);
    }
    cnorm_out[k] = s;
}

// ---------------------------------------------------------------------------
// Kernel B: fused fp32 GEMM + argmin.
// Each workgroup: 64 rows (n) x all 1024 codes. 256 threads, 4x4 reg tile.
// LDS: zt[256][64] (64KB) + ct[32][64] (8KB) + cn[1024] (4KB) = 77824B -> 2 blk/CU
#define TN 64
#define TK 64
#define DC 32

__global__ __launch_bounds__(256, 2)
void vq_argmin_kernel(const float* __restrict__ z, const float* __restrict__ cb,
                      const float* __restrict__ cnorm_g, float* __restrict__ idx_out) {
    __shared__ float zt[DD * TN];   // [d][n]
    __shared__ float ct[DC * TK];   // [d_chunk][k]; reused as reduction buf at end
    __shared__ float cn[KK];

    const int t   = threadIdx.x;
    const int tn  = t & 15;         // row group
    const int tk  = t >> 4;         // col group
    const int tn4 = tn * 4;
    const int tk4 = tk * 4;

    const int n0  = blockIdx.x * TN;      // global row base (tile never crosses b)
    const int b   = n0 >> 10;
    const int nb0 = n0 & 1023;

    // ---- stage z tile: z[b, d, nb0 .. nb0+63] -> zt[d][0..63]
    {
        const float* zb = z + (size_t)b * DD * HWD;
#pragma unroll
        for (int r = 0; r < 16; ++r) {
            int idx = r * 256 + t;          // 4096 float4s
            int d   = idx >> 4;
            int q   = idx & 15;
            float4 v = *(const float4*)(zb + (size_t)d * HWD + nb0 + q * 4);
            *(float4*)&zt[d * TN + q * 4] = v;
        }
        // stage codebook norms
        *(float4*)&cn[t * 4] = *(const float4*)(cnorm_g + t * 4);
    }

    float bestv[4];
    int   bestk[4];
#pragma unroll
    for (int i = 0; i < 4; ++i) { bestv[i] = 3.0e38f; bestk[i] = 0; }

    for (int kt = 0; kt < KK / TK; ++kt) {
        const int k0 = kt * TK;
        float acc[16];
#pragma unroll
        for (int q = 0; q < 16; ++q) acc[q] = 0.f;

        for (int dc = 0; dc < DD / DC; ++dc) {
            __syncthreads();   // previous ct consumers done
            // stage ct[dd][kk] = cb[k0+kk][dc*32+dd]  (transpose on write)
#pragma unroll
            for (int r = 0; r < 2; ++r) {
                int idx = r * 256 + t;      // 512 float4s
                int kk  = idx >> 3;
                int q   = idx & 7;
                float4 v = *(const float4*)(cb + (size_t)(k0 + kk) * DD + dc * DC + q * 4);
                ct[(q * 4 + 0) * TK + kk] = v.x;
                ct[(q * 4 + 1) * TK + kk] = v.y;
                ct[(q * 4 + 2) * TK + kk] = v.z;
                ct[(q * 4 + 3) * TK + kk] = v.w;
            }
            __syncthreads();

#pragma unroll
            for (int dd = 0; dd < DC; ++dd) {
                float4 zv = *(const float4*)&zt[(dc * DC + dd) * TN + tn4];
                float4 cv = *(const float4*)&ct[dd * TK + tk4];
                float zr[4] = {zv.x, zv.y, zv.z, zv.w};
                float cr[4] = {cv.x, cv.y, cv.z, cv.w};
#pragma unroll
                for (int i = 0; i < 4; ++i)
#pragma unroll
                    for (int j = 0; j < 4; ++j)
                        acc[i * 4 + j] = fmaf(zr[i], cr[j], acc[i * 4 + j]);
            }
        }

        // distances for this k-tile: d = ||c||^2 - 2*S  (||z||^2 row-const)
#pragma unroll
        for (int j = 0; j < 4; ++j) {
            int   kg  = k0 + tk4 + j;
            float cnj = cn[kg];
#pragma unroll
            for (int i = 0; i < 4; ++i) {
                float dist = cnj - 2.0f * acc[i * 4 + j];
                if (dist < bestv[i]) { bestv[i] = dist; bestk[i] = kg; }  // strict < : first-min
            }
        }
    }

    // ---- cross-thread argmin reduction (16 tk threads share each row)
    __syncthreads();
    float* redv = ct;                  // [64][16] floats
    int*   redk = (int*)(ct + 1024);   // [64][16] ints  (8KB total = ct size)
#pragma unroll
    for (int i = 0; i < 4; ++i) {
        redv[(tn4 + i) * 16 + tk] = bestv[i];
        redk[(tn4 + i) * 16 + tk] = bestk[i];
    }
    __syncthreads();
    if (t < TN) {
        float bv = redv[t * 16];
        int   bk = redk[t * 16];
#pragma unroll
        for (int s = 1; s < 16; ++s) {
            float v  = redv[t * 16 + s];
            int   kc = redk[t * 16 + s];
            if (v < bv || (v == bv && kc < bk)) { bv = v; bk = kc; }
        }
        idx_out[n0 + t] = (float)bk;   // indices as float32 values
    }
}

// ---------------------------------------------------------------------------
// Kernel C: gather z_q = codebook[idx] (also overwrites cnorm scratch),
// plus commitment loss = 0.25 * mean((z - z_q)^2) via per-block atomic.
__global__ __launch_bounds__(256)
void vq_gather_loss_kernel(const float* __restrict__ z, const float* __restrict__ cb,
                           float* __restrict__ out) {
    const float* idxf  = out + IDX_OFF;
    float*       lossp = out + LOSS_OFF;

    float local = 0.f;
    const int stride = gridDim.x * blockDim.x;
    for (int o = blockIdx.x * 256 + threadIdx.x; o < ZQ_SIZE; o += stride) {
        int b  = o >> 18;              // / (D*HW)
        int d  = (o >> 10) & 255;
        int hw = o & 1023;
        int n  = (b << 10) | hw;
        int k  = (int)idxf[n];
        float v = cb[(size_t)k * DD + d];
        out[o] = v;
        float diff = z[o] - v;
        local = fmaf(diff, diff, local);
    }

    // wave then block reduction
#pragma unroll
    for (int off = 32; off > 0; off >>= 1) local += __shfl_down(local, off, 64);
    __shared__ float bl[4];
    if ((threadIdx.x & 63) == 0) bl[threadIdx.x >> 6] = local;
    __syncthreads();
    if (threadIdx.x == 0) {
        float s = bl[0] + bl[1] + bl[2] + bl[3];
        atomicAdd(lossp, s * (0.25f / (float)ZQ_SIZE));   // 0.25/2^23 exact
    }
}

// ---------------------------------------------------------------------------
extern "C" void kernel_launch(void* const* d_in, const int* in_sizes, int n_in,
                              void* d_out, int out_size, void* d_ws, size_t ws_size,
                              hipStream_t stream) {
    const float* z  = (const float*)d_in[0];
    const float* cb = (const float*)d_in[1];
    float* out = (float*)d_out;

    // cnorm scratch lives at the start of the z_q region; kernel C overwrites it.
    float* cnorm_scratch = out;

    // zero the loss accumulator (poisoned once; replays must re-zero)
    hipMemsetAsync((void*)(out + LOSS_OFF), 0, sizeof(float), stream);

    vq_cnorm_kernel<<<KK / 256, 256, 0, stream>>>(cb, cnorm_scratch);

    vq_argmin_kernel<<<NN / TN, 256, 0, stream>>>(z, cb, cnorm_scratch, out + IDX_OFF);

    vq_gather_loss_kernel<<<2048, 256, 0, stream>>>(z, cb, out);
}

// Round 2
// 286.327 us; speedup vs baseline: 1.2720x; 1.2720x over previous
//
#include <hip/hip_runtime.h>

// Problem constants (from reference setup_inputs)
#define BD  32                 // batch
#define DD  256                // embedding dim
#define HWD 1024               // H*W = 32*32
#define NN  (BD*HWD)           // 32768 vectors
#define KK  1024               // codebook entries
#define ZQ_SIZE (NN*DD)        // 8388608
#define IDX_OFF ZQ_SIZE
#define LOSS_OFF (ZQ_SIZE + NN)

// ---------------------------------------------------------------------------
// Kernel A: codebook row norms ||c_k||^2 -> scratch (start of z_q region,
// overwritten later by kernel C).
__global__ __launch_bounds__(256)
void vq_cnorm_kernel(const float* __restrict__ cb, float* __restrict__ cnorm_out) {
    int k = blockIdx.x * 256 + threadIdx.x;   // grid = 4 blocks -> k in [0,1024)
    const float4* row = (const float4*)(cb + (size_t)k * DD);
    float s = 0.f;
#pragma unroll
    for (int i = 0; i < DD / 4; ++i) {
        float4 v = row[i];
        s = fmaf(v.x, v.x, s);
        s = fmaf(v.y, v.y, s);
        s = fmaf(v.z, v.z, s);
        s = fmaf(v.w, v.w, s);
    }
    cnorm_out[k] = s;
}

// ---------------------------------------------------------------------------
// Kernel B: fused fp32 GEMM + argmin, 8x8 register tile (1 B LDS-read / FMA).
// Block: TN=64 rows x all 1024 codes (K-tiles of 256). 256 threads as
// 8 (tn, rows) x 32 (tk, cols); per-thread tile = {tn*4..+3, 32+tn*4..+3} x
// {tk*4..+3, 128+tk*4..+3}. d staged in chunks of 8 with register prefetch.
#define TN  64
#define TKT 256
#define NKT (KK / TKT)   // 4
#define DCC 8
#define NDC (DD / DCC)   // 32

__global__ __launch_bounds__(256, 2)
void vq_argmin_kernel(const float* __restrict__ z, const float* __restrict__ cb,
                      const float* __restrict__ cnorm_g, float* __restrict__ idx_out) {
    __shared__ float zt[DCC * TN];     // [dd][n]   2 KB
    __shared__ float ct[DCC * TKT];    // [dd][k]   8 KB
    __shared__ float cn[KK];           // 4 KB
    __shared__ float redv[TN * 33];    // padded reduction buffers
    __shared__ int   redk[TN * 33];

    const int t   = threadIdx.x;
    const int tn  = t & 7;          // row group 0..7
    const int tk  = t >> 3;         // col group 0..31
    const int n0  = blockIdx.x * TN;
    const int b   = n0 >> 10;
    const int nb0 = n0 & 1023;
    const float* zb = z + (size_t)b * DD * HWD;

    // stage codebook norms (consumed after first barrier inside the loop)
    *(float4*)&cn[t * 4] = *(const float4*)(cnorm_g + t * 4);

    float bestv[8];
    int   bestk[8];
#pragma unroll
    for (int i = 0; i < 8; ++i) { bestv[i] = 3.0e38f; bestk[i] = 0; }

    // staging thread roles
    const int zdd = t >> 4;             // 0..7 (threads t<128 stage z)
    const int zn4 = (t & 15) * 4;
    const int kk0 = t >> 1;             // 0..127
    const int q0  = t & 1;
    const int kk1 = 128 + (t >> 1);     // second c-chunk
    const int q1  = t & 1;

    float4 zreg, cr0, cr1;

    for (int kt = 0; kt < NKT; ++kt) {
        const int k0 = kt * TKT;
        float acc[64];
#pragma unroll
        for (int q = 0; q < 64; ++q) acc[q] = 0.f;

        // prefetch dc = 0
        if (t < 128) zreg = *(const float4*)(zb + (size_t)zdd * HWD + nb0 + zn4);
        cr0 = *(const float4*)(cb + (size_t)(k0 + kk0) * DD + q0 * 4);
        cr1 = *(const float4*)(cb + (size_t)(k0 + kk1) * DD + q1 * 4);

        for (int dc = 0; dc < NDC; ++dc) {
            __syncthreads();   // previous chunk's readers done
            if (t < 128) *(float4*)&zt[zdd * TN + zn4] = zreg;
            ct[(q0 * 4 + 0) * TKT + kk0] = cr0.x;
            ct[(q0 * 4 + 1) * TKT + kk0] = cr0.y;
            ct[(q0 * 4 + 2) * TKT + kk0] = cr0.z;
            ct[(q0 * 4 + 3) * TKT + kk0] = cr0.w;
            ct[(q1 * 4 + 0) * TKT + kk1] = cr1.x;
            ct[(q1 * 4 + 1) * TKT + kk1] = cr1.y;
            ct[(q1 * 4 + 2) * TKT + kk1] = cr1.z;
            ct[(q1 * 4 + 3) * TKT + kk1] = cr1.w;
            __syncthreads();

            // prefetch next chunk (hidden under the 512-FMA compute below)
            int ndc = dc + 1, nk0 = k0;
            bool have = true;
            if (ndc == NDC) { ndc = 0; nk0 += TKT; have = (kt + 1 < NKT); }
            if (have) {
                if (t < 128)
                    zreg = *(const float4*)(zb + (size_t)(ndc * DCC + zdd) * HWD + nb0 + zn4);
                cr0 = *(const float4*)(cb + (size_t)(nk0 + kk0) * DD + ndc * DCC + q0 * 4);
                cr1 = *(const float4*)(cb + (size_t)(nk0 + kk1) * DD + ndc * DCC + q1 * 4);
            }

#pragma unroll
            for (int dd = 0; dd < DCC; ++dd) {
                float4 za = *(float4*)&zt[dd * TN + tn * 4];
                float4 zc = *(float4*)&zt[dd * TN + 32 + tn * 4];
                float4 ca = *(float4*)&ct[dd * TKT + tk * 4];
                float4 cc = *(float4*)&ct[dd * TKT + 128 + tk * 4];
                float zr[8] = {za.x, za.y, za.z, za.w, zc.x, zc.y, zc.z, zc.w};
                float cr[8] = {ca.x, ca.y, ca.z, ca.w, cc.x, cc.y, cc.z, cc.w};
#pragma unroll
                for (int i = 0; i < 8; ++i)
#pragma unroll
                    for (int j = 0; j < 8; ++j)
                        acc[i * 8 + j] = fmaf(zr[i], cr[j], acc[i * 8 + j]);
            }
        }

        // distances for this k-tile: d = ||c||^2 - 2*S  (||z||^2 row-const).
        // k ascending within thread (j=0..3 then +128 block), kt ascending;
        // strict < keeps the first minimum.
#pragma unroll
        for (int j = 0; j < 8; ++j) {
            int   kg  = k0 + tk * 4 + (j & 3) + (j >> 2) * 128;
            float cnj = cn[kg];
#pragma unroll
            for (int i = 0; i < 8; ++i) {
                float dist = cnj - 2.0f * acc[i * 8 + j];
                if (dist < bestv[i]) { bestv[i] = dist; bestk[i] = kg; }
            }
        }
    }

    // ---- cross-thread argmin reduction (32 tk-threads share each row)
    __syncthreads();
#pragma unroll
    for (int i = 0; i < 8; ++i) {
        int nl = tn * 4 + (i & 3) + (i >> 2) * 32;
        redv[nl * 33 + tk] = bestv[i];
        redk[nl * 33 + tk] = bestk[i];
    }
    __syncthreads();
    if (t < TN) {
        float bv = redv[t * 33];
        int   bk = redk[t * 33];
#pragma unroll
        for (int s = 1; s < 32; ++s) {
            float v  = redv[t * 33 + s];
            int   kc = redk[t * 33 + s];
            if (v < bv || (v == bv && kc < bk)) { bv = v; bk = kc; }
        }
        idx_out[n0 + t] = (float)bk;   // indices as float32 values
    }
}

// ---------------------------------------------------------------------------
// Kernel C: gather z_q = codebook[idx] (also overwrites cnorm scratch),
// plus commitment loss = 0.25 * mean((z - z_q)^2) via per-block atomic.
__global__ __launch_bounds__(256)
void vq_gather_loss_kernel(const float* __restrict__ z, const float* __restrict__ cb,
                           float* __restrict__ out) {
    const float* idxf  = out + IDX_OFF;
    float*       lossp = out + LOSS_OFF;

    float local = 0.f;
    const int stride = gridDim.x * blockDim.x;
    for (int o = blockIdx.x * 256 + threadIdx.x; o < ZQ_SIZE; o += stride) {
        int b  = o >> 18;              // / (D*HW)
        int d  = (o >> 10) & 255;
        int hw = o & 1023;
        int n  = (b << 10) | hw;
        int k  = (int)idxf[n];
        float v = cb[(size_t)k * DD + d];
        out[o] = v;
        float diff = z[o] - v;
        local = fmaf(diff, diff, local);
    }

    // wave then block reduction
#pragma unroll
    for (int off = 32; off > 0; off >>= 1) local += __shfl_down(local, off, 64);
    __shared__ float bl[4];
    if ((threadIdx.x & 63) == 0) bl[threadIdx.x >> 6] = local;
    __syncthreads();
    if (threadIdx.x == 0) {
        float s = bl[0] + bl[1] + bl[2] + bl[3];
        atomicAdd(lossp, s * (0.25f / (float)ZQ_SIZE));   // 0.25/2^23 exact
    }
}

// ---------------------------------------------------------------------------
extern "C" void kernel_launch(void* const* d_in, const int* in_sizes, int n_in,
                              void* d_out, int out_size, void* d_ws, size_t ws_size,
                              hipStream_t stream) {
    const float* z  = (const float*)d_in[0];
    const float* cb = (const float*)d_in[1];
    float* out = (float*)d_out;

    // cnorm scratch lives at the start of the z_q region; kernel C overwrites it.
    float* cnorm_scratch = out;

    // zero the loss accumulator (poisoned once; replays must re-zero)
    hipMemsetAsync((void*)(out + LOSS_OFF), 0, sizeof(float), stream);

    vq_cnorm_kernel<<<KK / 256, 256, 0, stream>>>(cb, cnorm_scratch);

    vq_argmin_kernel<<<NN / TN, 256, 0, stream>>>(z, cb, cnorm_scratch, out + IDX_OFF);

    vq_gather_loss_kernel<<<2048, 256, 0, stream>>>(z, cb, out);
}

// Round 3
// 146.906 us; speedup vs baseline: 2.4791x; 1.9490x over previous
//
#include <hip/hip_runtime.h>
#include <hip/hip_bf16.h>

#define DD  256
#define HWD 1024
#define NN  32768
#define KK  1024
#define ZQ_SIZE (NN*DD)
#define IDX_OFF ZQ_SIZE
#define LOSS_OFF (ZQ_SIZE + NN)

// scratch layout (bytes) inside the z_q region of d_out (overwritten by gather at the end)
#define CBHI_OFF   0
#define CBLO_OFF   (KK*DD*2)            // 512 KB
#define CNORM_OFF  (KK*DD*4)            // 1 MB
#define ROWREC_OFF (CNORM_OFF + KK*4)   // 1 MB + 4 KB

#define TH_REFINE 0.01f

typedef __attribute__((ext_vector_type(8))) short s16x8;
typedef __attribute__((ext_vector_type(4))) float f32x4;

__device__ __forceinline__ void gload16(const void* g, void* l) {
    __builtin_amdgcn_global_load_lds(
        (const __attribute__((address_space(1))) void*)g,
        (__attribute__((address_space(3))) void*)l, 16, 0, 0);
}
__device__ __forceinline__ unsigned short f2bf(float x) {
    __hip_bfloat16 h = __float2bfloat16(x);
    return *reinterpret_cast<unsigned short*>(&h);
}
__device__ __forceinline__ float bf2f(unsigned short u) {
    __hip_bfloat16 h; *reinterpret_cast<unsigned short*>(&h) = u;
    return __bfloat162float(h);
}

// ---------------------------------------------------------------------------
// A: codebook -> bf16 hi/lo split + row norms
__global__ __launch_bounds__(256)
void vq_prep_kernel(const float* __restrict__ cb, unsigned char* __restrict__ scratch) {
    unsigned short* cbh = (unsigned short*)(scratch + CBHI_OFF);
    unsigned short* cbl = (unsigned short*)(scratch + CBLO_OFF);
    float* cn = (float*)(scratch + CNORM_OFF);
    int t = threadIdx.x;
    int row = blockIdx.x * 16 + (t >> 4);   // grid 64
    int dq  = t & 15;
    const float* rp = cb + (size_t)row * DD + dq * 16;
    float nrm = 0.f;
    __attribute__((aligned(16))) unsigned short h[16];
    __attribute__((aligned(16))) unsigned short l[16];
#pragma unroll
    for (int i = 0; i < 4; ++i) {
        float4 v = *(const float4*)(rp + i * 4);
        float xs[4] = {v.x, v.y, v.z, v.w};
#pragma unroll
        for (int j = 0; j < 4; ++j) {
            float x = xs[j];
            unsigned short hi = f2bf(x);
            h[i*4+j] = hi;
            l[i*4+j] = f2bf(x - bf2f(hi));
            nrm = fmaf(x, x, nrm);
        }
    }
    *(uint4*)&cbh[row*DD + dq*16]     = *(uint4*)&h[0];
    *(uint4*)&cbh[row*DD + dq*16 + 8] = *(uint4*)&h[8];
    *(uint4*)&cbl[row*DD + dq*16]     = *(uint4*)&l[0];
    *(uint4*)&cbl[row*DD + dq*16 + 8] = *(uint4*)&l[8];
#pragma unroll
    for (int m = 1; m < 16; m <<= 1) nrm += __shfl_xor(nrm, m, 64);
    if (dq == 0) cn[row] = nrm;
}

// ---------------------------------------------------------------------------
// B: MFMA distance-argmin. 64 n-rows x all 1024 k per block, 4 waves.
// 3-term bf16 split GEMM, per-(lane,row-slot) top-2, merged to per-row top-2.
__global__ __launch_bounds__(256)
void vq_mfma_argmin_kernel(const float* __restrict__ z, unsigned char* __restrict__ scratch) {
    const unsigned char* cbh_b = scratch + CBHI_OFF;
    const unsigned char* cbl_b = scratch + CBLO_OFF;
    const float* cn_g = (const float*)(scratch + CNORM_OFF);
    float* rowrec = (float*)(scratch + ROWREC_OFF);

    __shared__ unsigned short zhi[64 * 256];        // 32 KB, swizzled [n][d]
    __shared__ unsigned short zlo[64 * 256];        // 32 KB
    __shared__ unsigned short cbuf[2][2][128 * 64]; // 64 KB  [buf][hi/lo][k][d-chunk]
    __shared__ float red[4][64][4];                 // 4 KB

    const int t = threadIdx.x;
    const int w = t >> 6;
    const int lane = t & 63;
    const int ln15 = lane & 15;
    const int lh = lane >> 4;
    const int swz8 = (ln15 & 7) << 3;               // ushort-index xor for reads

    const int n0 = blockIdx.x * 64;                 // grid 512 (tiles never cross batch)
    const int b  = n0 >> 10;
    const int hw0 = n0 & 1023;
    const float* zb = z + (size_t)b * DD * HWD + hw0;

    // staging lane constants: slice = 8 k-rows x 64 d (1 KB). linear LDS dest,
    // source pre-swizzled so reads at (d*2 ^ ((k&7)<<4)) find cb[k][d].
    const int sl_k = lane >> 3;
    const int sxor = ((lane & 7) ^ (sl_k & 7)) << 4;

    // ---- prologue: chunk 0 -> buf0, plus z tile (fp32 -> bf16 hi/lo, transposed+swizzled)
#pragma unroll
    for (int si = 0; si < 8; ++si) {
        int slice = w * 8 + si;
        int p = slice >> 4, s8 = slice & 15;
        const unsigned char* srcb = (p ? cbl_b : cbh_b)
            + (size_t)(s8 * 8 + sl_k) * 512 + sxor;          // kbase=0, dbyte=0
        gload16(srcb, &cbuf[0][p][s8 * 512]);
    }
    {
        const int zn = t & 63, zph = t >> 6;
        for (int dd = 0; dd < 64; ++dd) {
            int d = dd * 4 + zph;
            float x = zb[(size_t)d * HWD + zn];
            unsigned short hi = f2bf(x);
            unsigned short lo = f2bf(x - bf2f(hi));
            int idx = zn * 256 + (d ^ ((zn & 7) << 3));
            zhi[idx] = hi; zlo[idx] = lo;
        }
    }
    __syncthreads();

    f32x4 acc[4][2];
#pragma unroll
    for (int nf = 0; nf < 4; ++nf)
#pragma unroll
        for (int kf = 0; kf < 2; ++kf) acc[nf][kf] = {0.f, 0.f, 0.f, 0.f};

    float v1[16], k1[16], v2[16], k2[16];
#pragma unroll
    for (int s = 0; s < 16; ++s) { v1[s] = 3e38f; v2[s] = 3e38f; k1[s] = 0.f; k2[s] = 0.f; }

    for (int c = 0; c < 32; ++c) {                  // chunk = kstep*4 + dchunk
        const int buf = c & 1;
        if (c < 31) {                               // prefetch next chunk (async, lands during compute)
            const int cnx = c + 1;
            const int nb = cnx & 1;
            const size_t kb = (size_t)(cnx >> 2) * 128 * 512;
            const int db = (cnx & 3) * 128;
#pragma unroll
            for (int si = 0; si < 8; ++si) {
                int slice = w * 8 + si;
                int p = slice >> 4, s8 = slice & 15;
                const unsigned char* srcb = (p ? cbl_b : cbh_b)
                    + kb + (size_t)(s8 * 8 + sl_k) * 512 + db + sxor;
                gload16(srcb, &cbuf[nb][p][s8 * 512]);
            }
        }
        const int dc = c & 3;
        const unsigned short* ch = &cbuf[buf][0][0];
        const unsigned short* cl = &cbuf[buf][1][0];
#pragma unroll
        for (int ds = 0; ds < 2; ++ds) {
            s16x8 bh[2], bl2[2];
#pragma unroll
            for (int kf = 0; kf < 2; ++kf) {
                int kl = w * 32 + kf * 16 + ln15;
                int ib = kl * 64 + ((ds * 32 + lh * 8) ^ swz8);
                bh[kf]  = *(const s16x8*)&ch[ib];
                bl2[kf] = *(const s16x8*)&cl[ib];
            }
#pragma unroll
            for (int nf = 0; nf < 4; ++nf) {
                int dg = dc * 64 + ds * 32 + lh * 8;
                int ia = (nf * 16 + ln15) * 256 + (dg ^ swz8);
                s16x8 ah = *(const s16x8*)&zhi[ia];
                s16x8 al = *(const s16x8*)&zlo[ia];
#pragma unroll
                for (int kf = 0; kf < 2; ++kf) {
                    acc[nf][kf] = __builtin_amdgcn_mfma_f32_16x16x32_bf16(ah, bh[kf],  acc[nf][kf], 0, 0, 0);
                    acc[nf][kf] = __builtin_amdgcn_mfma_f32_16x16x32_bf16(al, bh[kf],  acc[nf][kf], 0, 0, 0);
                    acc[nf][kf] = __builtin_amdgcn_mfma_f32_16x16x32_bf16(ah, bl2[kf], acc[nf][kf], 0, 0, 0);
                }
            }
        }
        if (dc == 3) {                              // k-step epilogue: dist + top-2
            const int kstep = c >> 2;
#pragma unroll
            for (int kf = 0; kf < 2; ++kf) {
                int kg = kstep * 128 + w * 32 + kf * 16 + ln15;
                float cnv = cn_g[kg];
                float kgf = (float)kg;
#pragma unroll
                for (int nf = 0; nf < 4; ++nf)
#pragma unroll
                    for (int r = 0; r < 4; ++r) {
                        float dist = fmaf(-2.f, acc[nf][kf][r], cnv);
                        int s = nf * 4 + r;
                        bool b1 = dist < v1[s];
                        bool b2 = dist < v2[s];
                        float nv2 = b1 ? v1[s] : (b2 ? dist : v2[s]);
                        float nk2 = b1 ? k1[s] : (b2 ? kgf  : k2[s]);
                        v2[s] = nv2; k2[s] = nk2;
                        v1[s] = b1 ? dist : v1[s];
                        k1[s] = b1 ? kgf  : k1[s];
                    }
            }
#pragma unroll
            for (int nf = 0; nf < 4; ++nf)
#pragma unroll
                for (int kf = 0; kf < 2; ++kf) acc[nf][kf] = {0.f, 0.f, 0.f, 0.f};
        }
        __syncthreads();   // drains this iter's prefetch (had full compute to land) + buffer handoff
    }

    // merge top-2 across the 16 lanes sharing each row group (cols differ per lane)
#pragma unroll
    for (int m = 1; m < 16; m <<= 1) {
#pragma unroll
        for (int s = 0; s < 16; ++s) {
            float ov1 = __shfl_xor(v1[s], m, 64);
            float ok1 = __shfl_xor(k1[s], m, 64);
            float ov2 = __shfl_xor(v2[s], m, 64);
            float ok2 = __shfl_xor(k2[s], m, 64);
            bool alt = ov1 < v1[s];
            float nv1 = alt ? ov1 : v1[s];
            float nk1 = alt ? ok1 : k1[s];
            float cnd = alt ? v1[s] : ov1;
            float cndk = alt ? k1[s] : ok1;
            float oth = alt ? ov2 : v2[s];
            float othk = alt ? ok2 : k2[s];
            bool sec = oth < cnd;
            v1[s] = nv1; k1[s] = nk1;
            v2[s] = sec ? oth : cnd;
            k2[s] = sec ? othk : cndk;
        }
    }
    if (ln15 == 0) {
#pragma unroll
        for (int nf = 0; nf < 4; ++nf)
#pragma unroll
            for (int r = 0; r < 4; ++r) {
                int s = nf * 4 + r;
                int nl = nf * 16 + lh * 4 + r;     // row = 4*(lane>>4)+reg per C-layout
                red[w][nl][0] = v1[s]; red[w][nl][1] = k1[s];
                red[w][nl][2] = v2[s]; red[w][nl][3] = k2[s];
            }
    }
    __syncthreads();
    if (t < 64) {
        float a1 = red[0][t][0], ak1 = red[0][t][1], a2 = red[0][t][2], ak2 = red[0][t][3];
#pragma unroll
        for (int ww = 1; ww < 4; ++ww) {
            float b1v = red[ww][t][0], bk1 = red[ww][t][1];
            float b2v = red[ww][t][2], bk2 = red[ww][t][3];
            bool alt = b1v < a1;
            float nv1 = alt ? b1v : a1, nk1 = alt ? bk1 : ak1;
            float cnd = alt ? a1 : b1v, cndk = alt ? ak1 : bk1;
            float oth = alt ? b2v : a2, othk = alt ? bk2 : ak2;
            bool sec = oth < cnd;
            a1 = nv1; ak1 = nk1;
            a2 = sec ? oth : cnd; ak2 = sec ? othk : cndk;
        }
        float4 rec; rec.x = a1; rec.y = ak1; rec.z = a2; rec.w = ak2;
        *(float4*)&rowrec[(size_t)(n0 + t) * 4] = rec;
    }
}

// ---------------------------------------------------------------------------
// R: ambiguous rows (approx gap <= TH) -> exact fp32 recheck of top-2 (first-min)
__global__ __launch_bounds__(256)
void vq_refine_kernel(const float* __restrict__ z, const float* __restrict__ cb,
                      const unsigned char* __restrict__ scratch, float* __restrict__ idx_out) {
    const float* rowrec = (const float*)(scratch + ROWREC_OFF);
    int n = blockIdx.x * 256 + threadIdx.x;       // grid 128
    int lane = threadIdx.x & 63;
    float4 rec = *(const float4*)&rowrec[(size_t)n * 4];
    bool need = (rec.z - rec.x) <= TH_REFINE;
    if (!need) idx_out[n] = rec.y;
    unsigned long long mask = __ballot(need);
    while (mask) {
        int li = __ffsll(mask) - 1;
        mask &= mask - 1;
        int nn  = __shfl(n, li);
        int kk1 = (int)__shfl(rec.y, li);
        int kk2 = (int)__shfl(rec.w, li);
        int bb = nn >> 10, hw = nn & 1023;
        const float* zp  = z  + (size_t)bb * DD * HWD + hw;
        const float* c1p = cb + (size_t)kk1 * DD;
        const float* c2p = cb + (size_t)kk2 * DD;
        float s1 = 0.f, s2 = 0.f;
#pragma unroll
        for (int j = 0; j < 4; ++j) {
            int d = lane + 64 * j;
            float zv = zp[(size_t)d * HWD];
            float t1 = zv - c1p[d]; s1 = fmaf(t1, t1, s1);
            float t2 = zv - c2p[d]; s2 = fmaf(t2, t2, s2);
        }
#pragma unroll
        for (int m = 32; m >= 1; m >>= 1) { s1 += __shfl_xor(s1, m, 64); s2 += __shfl_xor(s2, m, 64); }
        int choice = (s1 < s2) ? kk1 : ((s2 < s1) ? kk2 : (kk1 < kk2 ? kk1 : kk2));
        if (lane == 0) idx_out[nn] = (float)choice;
    }
}

// ---------------------------------------------------------------------------
// C: tiled gather (LDS row cache, coalesced writes) + commitment loss
__global__ __launch_bounds__(256)
void vq_gather_loss_kernel(const float* __restrict__ z, const float* __restrict__ cb,
                           float* __restrict__ out) {
    const float* idxf = out + IDX_OFF;
    float* lossp = out + LOSS_OFF;
    __shared__ float crow[64][257];
    __shared__ int kidx[64];
    __shared__ float bl[4];
    int t = threadIdx.x;
    int w = t >> 6, lane = t & 63;
    int n0 = blockIdx.x * 64;                      // grid 512
    int b = n0 >> 10, hw0 = n0 & 1023;
    if (t < 64) kidx[t] = (int)idxf[n0 + t];
    __syncthreads();
    for (int i = 0; i < 16; ++i) {                 // stage 64 code rows (coalesced 1KB/wave)
        int r = w * 16 + i;
        int k = kidx[r];
        float4 v = *(const float4*)(cb + (size_t)k * DD + lane * 4);
        crow[r][lane * 4 + 0] = v.x; crow[r][lane * 4 + 1] = v.y;
        crow[r][lane * 4 + 2] = v.z; crow[r][lane * 4 + 3] = v.w;
    }
    __syncthreads();
    float local = 0.f;
    const int zph = t >> 6, hwl = t & 63;
    for (int dd = 0; dd < 64; ++dd) {
        int d = dd * 4 + zph;
        float val = crow[hwl][d];                  // banks (hwl+d)%32: 2-way, free
        size_t o = (size_t)b * (DD * HWD) + (size_t)d * HWD + hw0 + hwl;
        float zv = z[o];
        out[o] = val;
        float df = zv - val;
        local = fmaf(df, df, local);
    }
#pragma unroll
    for (int m = 32; m >= 1; m >>= 1) local += __shfl_xor(local, m, 64);
    if (lane == 0) bl[w] = local;
    __syncthreads();
    if (t == 0) {
        float s = bl[0] + bl[1] + bl[2] + bl[3];
        atomicAdd(lossp, s * (0.25f / (float)ZQ_SIZE));
    }
}

// ---------------------------------------------------------------------------
extern "C" void kernel_launch(void* const* d_in, const int* in_sizes, int n_in,
                              void* d_out, int out_size, void* d_ws, size_t ws_size,
                              hipStream_t stream) {
    const float* z  = (const float*)d_in[0];
    const float* cb = (const float*)d_in[1];
    float* out = (float*)d_out;
    unsigned char* scratch = (unsigned char*)d_out;   // lives in z_q region, overwritten by gather

    hipMemsetAsync((void*)(out + LOSS_OFF), 0, sizeof(float), stream);

    vq_prep_kernel<<<64, 256, 0, stream>>>(cb, scratch);
    vq_mfma_argmin_kernel<<<512, 256, 0, stream>>>(z, scratch);
    vq_refine_kernel<<<128, 256, 0, stream>>>(z, cb, scratch, out + IDX_OFF);
    vq_gather_loss_kernel<<<512, 256, 0, stream>>>(z, cb, out);
}

// Round 4
// 103.264 us; speedup vs baseline: 3.5269x; 1.4226x over previous
//
#include <hip/hip_runtime.h>
#include <hip/hip_bf16.h>

#define DD  256
#define HWD 1024
#define NN  32768
#define KK  1024
#define ZQ_SIZE (NN*DD)
#define IDX_OFF ZQ_SIZE
#define LOSS_OFF (ZQ_SIZE + NN)

// scratch layout (bytes) inside the z_q region of d_out (overwritten by gather at the end)
#define CBHI_OFF   0
#define CBLO_OFF   (KK*DD*2)            // 512 KB
#define CNORM_OFF  (KK*DD*4)            // 1 MB
#define ROWREC_OFF (CNORM_OFF + KK*4)   // 1 MB + 4 KB

#define TH_REFINE 0.01f

typedef __attribute__((ext_vector_type(8))) short s16x8;
typedef __attribute__((ext_vector_type(4))) float f32x4;

__device__ __forceinline__ void gload16(const void* g, void* l) {
    __builtin_amdgcn_global_load_lds(
        (const __attribute__((address_space(1))) void*)g,
        (__attribute__((address_space(3))) void*)l, 16, 0, 0);
}
__device__ __forceinline__ unsigned short f2bf(float x) {
    __hip_bfloat16 h = __float2bfloat16(x);
    return *reinterpret_cast<unsigned short*>(&h);
}
__device__ __forceinline__ float bf2f(unsigned short u) {
    __hip_bfloat16 h; *reinterpret_cast<unsigned short*>(&h) = u;
    return __bfloat162float(h);
}

// ---------------------------------------------------------------------------
// A: codebook -> bf16 hi/lo split + row norms (plain row-major; argmin kernel
// applies the LDS swizzle via pre-swizzled global source addresses).
__global__ __launch_bounds__(256)
void vq_prep_kernel(const float* __restrict__ cb, unsigned char* __restrict__ scratch) {
    unsigned short* cbh = (unsigned short*)(scratch + CBHI_OFF);
    unsigned short* cbl = (unsigned short*)(scratch + CBLO_OFF);
    float* cn = (float*)(scratch + CNORM_OFF);
    int t = threadIdx.x;
    int row = blockIdx.x * 16 + (t >> 4);   // grid 64
    int dq  = t & 15;
    const float* rp = cb + (size_t)row * DD + dq * 16;
    float nrm = 0.f;
    __attribute__((aligned(16))) unsigned short h[16];
    __attribute__((aligned(16))) unsigned short l[16];
#pragma unroll
    for (int i = 0; i < 4; ++i) {
        float4 v = *(const float4*)(rp + i * 4);
        float xs[4] = {v.x, v.y, v.z, v.w};
#pragma unroll
        for (int j = 0; j < 4; ++j) {
            float x = xs[j];
            unsigned short hi = f2bf(x);
            h[i*4+j] = hi;
            l[i*4+j] = f2bf(x - bf2f(hi));
            nrm = fmaf(x, x, nrm);
        }
    }
    *(uint4*)&cbh[row*DD + dq*16]     = *(uint4*)&h[0];
    *(uint4*)&cbh[row*DD + dq*16 + 8] = *(uint4*)&h[8];
    *(uint4*)&cbl[row*DD + dq*16]     = *(uint4*)&l[0];
    *(uint4*)&cbl[row*DD + dq*16 + 8] = *(uint4*)&l[8];
#pragma unroll
    for (int m = 1; m < 16; m <<= 1) nrm += __shfl_xor(nrm, m, 64);
    if (dq == 0) cn[row] = nrm;
}

// ---------------------------------------------------------------------------
// B: MFMA distance-argmin. 512 threads = 8 waves; 4 row-groups x 2 k-half
// waves; 128 rows/block, grid 256 (1 block/CU, 2 waves/SIMD).
// z A-fragments (hi/lo) register-resident; codebook double-buffered in LDS,
// one barrier per 32-k tile, prefetch issued before compute.
__global__ __launch_bounds__(512, 2)
void vq_mfma_argmin_kernel(const float* __restrict__ z, unsigned char* __restrict__ scratch) {
    const unsigned char* cbh_b = scratch + CBHI_OFF;
    const unsigned char* cbl_b = scratch + CBLO_OFF;
    const float* cn_g = (const float*)(scratch + CNORM_OFF);
    float* rowrec = (float*)(scratch + ROWREC_OFF);

    __shared__ short cbuf[2][2][32 * 256];   // [buf][hi/lo][k][d] 64 KB, swizzled
    __shared__ float red[8][32][4];          // 4 KB

    const int t     = threadIdx.x;
    const int w     = t >> 6;
    const int lane  = t & 63;
    const int ln15  = lane & 15;
    const int lh    = lane >> 4;
    const int g     = w >> 1;        // row-group 0..3 (32 rows each)
    const int khalf = w & 1;         // which 16 of each 32-k tile

    const int n0  = blockIdx.x * 128;
    const int b   = n0 >> 10;
    const int hw0 = n0 & 1023;

    // staging lane constants (gload16: per-lane source, linear LDS dest)
    const int ksub  = lane >> 5;     // 0/1: which row of the lane-pair
    const int chunk = lane & 31;     // 16B chunk within the 512B row

    // read-side constants
    const int klr   = khalf * 16 + ln15;          // B-frag k row in tile
    const int rbase = klr * 256;                  // shorts
    const int rxor  = (klr & 7) << 3;             // swizzle (short units)

    // ---- prologue: stage tile 0, load z A-fragments (hi/lo) into registers
#pragma unroll
    for (int si = 0; si < 4; ++si) {
        int gi = w * 4 + si;
        int p  = gi >> 4, rp = gi & 15;
        int kl = rp * 2 + ksub;
        const unsigned char* src = (p ? cbl_b : cbh_b)
            + (size_t)kl * 512 + ((chunk ^ (kl & 7)) << 4);
        gload16(src, &cbuf[0][p][rp * 2 * 256]);
    }

    s16x8 ah[2][8], al[2][8];
    {
        const float* zcol = z + (size_t)b * DD * HWD + hw0 + g * 32 + ln15;
#pragma unroll
        for (int nf = 0; nf < 2; ++nf) {
            const float* zp = zcol + nf * 16;
#pragma unroll
            for (int ds = 0; ds < 8; ++ds) {
                const int d0 = ds * 32 + lh * 8;
#pragma unroll
                for (int j = 0; j < 8; ++j) {
                    float x = zp[(size_t)(d0 + j) * HWD];
                    unsigned short hi = f2bf(x);
                    unsigned short lo = f2bf(x - bf2f(hi));
                    ah[nf][ds][j] = (short)hi;
                    al[nf][ds][j] = (short)lo;
                }
            }
        }
    }
    __syncthreads();

    float v1[8], k1[8], v2[8], k2[8];
#pragma unroll
    for (int s = 0; s < 8; ++s) { v1[s] = 3e38f; v2[s] = 3e38f; k1[s] = 0.f; k2[s] = 0.f; }

    for (int kt = 0; kt < 32; ++kt) {
        const int cur = kt & 1;
        if (kt < 31) {                 // prefetch next tile into other buffer
            const int k0n = (kt + 1) * 32;
#pragma unroll
            for (int si = 0; si < 4; ++si) {
                int gi = w * 4 + si;
                int p  = gi >> 4, rp = gi & 15;
                int kl = rp * 2 + ksub;
                const unsigned char* src = (p ? cbl_b : cbh_b)
                    + (size_t)(k0n + kl) * 512 + ((chunk ^ (kl & 7)) << 4);
                gload16(src, &cbuf[cur ^ 1][p][rp * 2 * 256]);
            }
        }

        f32x4 acc0 = {0.f, 0.f, 0.f, 0.f};
        f32x4 acc1 = {0.f, 0.f, 0.f, 0.f};
        const short* ch = &cbuf[cur][0][0];
        const short* cl = &cbuf[cur][1][0];
#pragma unroll
        for (int ds = 0; ds < 8; ++ds) {
            const int ib = rbase + ((ds * 32 + lh * 8) ^ rxor);
            s16x8 bh = *(const s16x8*)&ch[ib];
            s16x8 bl = *(const s16x8*)&cl[ib];
            acc0 = __builtin_amdgcn_mfma_f32_16x16x32_bf16(ah[0][ds], bh, acc0, 0, 0, 0);
            acc1 = __builtin_amdgcn_mfma_f32_16x16x32_bf16(ah[1][ds], bh, acc1, 0, 0, 0);
            acc0 = __builtin_amdgcn_mfma_f32_16x16x32_bf16(al[0][ds], bh, acc0, 0, 0, 0);
            acc1 = __builtin_amdgcn_mfma_f32_16x16x32_bf16(al[1][ds], bh, acc1, 0, 0, 0);
            acc0 = __builtin_amdgcn_mfma_f32_16x16x32_bf16(ah[0][ds], bl, acc0, 0, 0, 0);
            acc1 = __builtin_amdgcn_mfma_f32_16x16x32_bf16(ah[1][ds], bl, acc1, 0, 0, 0);
        }

        // top-2 update: per lane one col kg, 8 row-slots (nf*4 + r)
        {
            const int kg = kt * 32 + khalf * 16 + ln15;
            const float cnv = cn_g[kg];
            const float kgf = (float)kg;
#pragma unroll
            for (int s = 0; s < 8; ++s) {
                float a = (s < 4) ? acc0[s] : acc1[s - 4];
                float dist = fmaf(-2.f, a, cnv);
                bool b1 = dist < v1[s];
                bool b2 = dist < v2[s];
                float nv2 = b1 ? v1[s] : (b2 ? dist : v2[s]);
                float nk2 = b1 ? k1[s] : (b2 ? kgf  : k2[s]);
                v2[s] = nv2; k2[s] = nk2;
                v1[s] = b1 ? dist : v1[s];
                k1[s] = b1 ? kgf  : k1[s];
            }
        }
        __syncthreads();   // buffer handoff; drains prefetch issued before compute
    }

    // ---- merge top-2 across the 16 cols held by ln15 lanes
#pragma unroll
    for (int m = 1; m < 16; m <<= 1) {
#pragma unroll
        for (int s = 0; s < 8; ++s) {
            float ov1 = __shfl_xor(v1[s], m, 64);
            float ok1 = __shfl_xor(k1[s], m, 64);
            float ov2 = __shfl_xor(v2[s], m, 64);
            float ok2 = __shfl_xor(k2[s], m, 64);
            bool alt = ov1 < v1[s];
            float nv1 = alt ? ov1 : v1[s];
            float nk1 = alt ? ok1 : k1[s];
            float cnd = alt ? v1[s] : ov1;
            float cndk = alt ? k1[s] : ok1;
            float oth = alt ? ov2 : v2[s];
            float othk = alt ? ok2 : k2[s];
            bool sec = oth < cnd;
            v1[s] = nv1; k1[s] = nk1;
            v2[s] = sec ? oth : cnd;
            k2[s] = sec ? othk : cndk;
        }
    }
    if (ln15 == 0) {
#pragma unroll
        for (int s = 0; s < 8; ++s) {
            int nf = s >> 2, r = s & 3;
            int rl = nf * 16 + lh * 4 + r;      // row-local within group (C-layout)
            red[w][rl][0] = v1[s]; red[w][rl][1] = k1[s];
            red[w][rl][2] = v2[s]; red[w][rl][3] = k2[s];
        }
    }
    __syncthreads();
    if (t < 128) {                               // merge the 2 k-half waves per group
        int gg = t >> 5, rl = t & 31;
        float a1 = red[gg*2][rl][0], ak1 = red[gg*2][rl][1];
        float a2 = red[gg*2][rl][2], ak2 = red[gg*2][rl][3];
        float b1v = red[gg*2+1][rl][0], bk1 = red[gg*2+1][rl][1];
        float b2v = red[gg*2+1][rl][2], bk2 = red[gg*2+1][rl][3];
        bool alt = b1v < a1;
        float nv1 = alt ? b1v : a1, nk1 = alt ? bk1 : ak1;
        float cnd = alt ? a1 : b1v, cndk = alt ? ak1 : bk1;
        float oth = alt ? b2v : a2, othk = alt ? bk2 : ak2;
        bool sec = oth < cnd;
        float4 rec;
        rec.x = nv1; rec.y = nk1;
        rec.z = sec ? oth : cnd; rec.w = sec ? othk : cndk;
        *(float4*)&rowrec[(size_t)(n0 + t) * 4] = rec;
    }
}

// ---------------------------------------------------------------------------
// R: ambiguous rows (approx gap <= TH) -> exact fp32 recheck of top-2 (first-min)
__global__ __launch_bounds__(256)
void vq_refine_kernel(const float* __restrict__ z, const float* __restrict__ cb,
                      const unsigned char* __restrict__ scratch, float* __restrict__ idx_out) {
    const float* rowrec = (const float*)(scratch + ROWREC_OFF);
    int n = blockIdx.x * 256 + threadIdx.x;       // grid 128
    int lane = threadIdx.x & 63;
    float4 rec = *(const float4*)&rowrec[(size_t)n * 4];
    bool need = (rec.z - rec.x) <= TH_REFINE;
    if (!need) idx_out[n] = rec.y;
    unsigned long long mask = __ballot(need);
    while (mask) {
        int li = __ffsll(mask) - 1;
        mask &= mask - 1;
        int nn  = __shfl(n, li);
        int kk1 = (int)__shfl(rec.y, li);
        int kk2 = (int)__shfl(rec.w, li);
        int bb = nn >> 10, hw = nn & 1023;
        const float* zp  = z  + (size_t)bb * DD * HWD + hw;
        const float* c1p = cb + (size_t)kk1 * DD;
        const float* c2p = cb + (size_t)kk2 * DD;
        float s1 = 0.f, s2 = 0.f;
#pragma unroll
        for (int j = 0; j < 4; ++j) {
            int d = lane + 64 * j;
            float zv = zp[(size_t)d * HWD];
            float t1 = zv - c1p[d]; s1 = fmaf(t1, t1, s1);
            float t2 = zv - c2p[d]; s2 = fmaf(t2, t2, s2);
        }
#pragma unroll
        for (int m = 32; m >= 1; m >>= 1) { s1 += __shfl_xor(s1, m, 64); s2 += __shfl_xor(s2, m, 64); }
        int choice = (s1 < s2) ? kk1 : ((s2 < s1) ? kk2 : (kk1 < kk2 ? kk1 : kk2));
        if (lane == 0) idx_out[nn] = (float)choice;
    }
}

// ---------------------------------------------------------------------------
// C: tiled gather (LDS row cache, coalesced writes) + commitment loss
__global__ __launch_bounds__(256)
void vq_gather_loss_kernel(const float* __restrict__ z, const float* __restrict__ cb,
                           float* __restrict__ out) {
    const float* idxf = out + IDX_OFF;
    float* lossp = out + LOSS_OFF;
    __shared__ float crow[64][257];
    __shared__ int kidx[64];
    __shared__ float bl[4];
    int t = threadIdx.x;
    int w = t >> 6, lane = t & 63;
    int n0 = blockIdx.x * 64;                      // grid 512
    int b = n0 >> 10, hw0 = n0 & 1023;
    if (t < 64) kidx[t] = (int)idxf[n0 + t];
    __syncthreads();
    for (int i = 0; i < 16; ++i) {                 // stage 64 code rows (coalesced 1KB/wave)
        int r = w * 16 + i;
        int k = kidx[r];
        float4 v = *(const float4*)(cb + (size_t)k * DD + lane * 4);
        crow[r][lane * 4 + 0] = v.x; crow[r][lane * 4 + 1] = v.y;
        crow[r][lane * 4 + 2] = v.z; crow[r][lane * 4 + 3] = v.w;
    }
    __syncthreads();
    float local = 0.f;
    const int zph = t >> 6, hwl = t & 63;
    for (int dd = 0; dd < 64; ++dd) {
        int d = dd * 4 + zph;
        float val = crow[hwl][d];                  // banks (hwl+d)%32: 2-way, free
        size_t o = (size_t)b * (DD * HWD) + (size_t)d * HWD + hw0 + hwl;
        float zv = z[o];
        out[o] = val;
        float df = zv - val;
        local = fmaf(df, df, local);
    }
#pragma unroll
    for (int m = 32; m >= 1; m >>= 1) local += __shfl_xor(local, m, 64);
    if (lane == 0) bl[w] = local;
    __syncthreads();
    if (t == 0) {
        float s = bl[0] + bl[1] + bl[2] + bl[3];
        atomicAdd(lossp, s * (0.25f / (float)ZQ_SIZE));
    }
}

// ---------------------------------------------------------------------------
extern "C" void kernel_launch(void* const* d_in, const int* in_sizes, int n_in,
                              void* d_out, int out_size, void* d_ws, size_t ws_size,
                              hipStream_t stream) {
    const float* z  = (const float*)d_in[0];
    const float* cb = (const float*)d_in[1];
    float* out = (float*)d_out;
    unsigned char* scratch = (unsigned char*)d_out;   // z_q region, overwritten by gather

    hipMemsetAsync((void*)(out + LOSS_OFF), 0, sizeof(float), stream);

    vq_prep_kernel<<<64, 256, 0, stream>>>(cb, scratch);
    vq_mfma_argmin_kernel<<<256, 512, 0, stream>>>(z, scratch);
    vq_refine_kernel<<<128, 256, 0, stream>>>(z, cb, scratch, out + IDX_OFF);
    vq_gather_loss_kernel<<<512, 256, 0, stream>>>(z, cb, out);
}

// Round 5
// 93.869 us; speedup vs baseline: 3.8799x; 1.1001x over previous
//
#include <hip/hip_runtime.h>
#include <hip/hip_bf16.h>

#define DD  256
#define HWD 1024
#define NN  32768
#define KK  1024
#define ZQ_SIZE (NN*DD)
#define IDX_OFF ZQ_SIZE
#define LOSS_OFF (ZQ_SIZE + NN)

// scratch layout (bytes) inside the z_q region of d_out (overwritten by gather at the end)
#define CBHI_OFF   0
#define CBLO_OFF   (KK*DD*2)            // 512 KB
#define CNORM_OFF  (KK*DD*4)            // 1 MB
#define ROWREC_OFF (CNORM_OFF + KK*4)   // 1 MB + 4 KB

#define TH_REFINE 0.01f

typedef __attribute__((ext_vector_type(8))) short s16x8;
typedef __attribute__((ext_vector_type(4))) float f32x4;

__device__ __forceinline__ void gload16(const void* g, void* l) {
    __builtin_amdgcn_global_load_lds(
        (const __attribute__((address_space(1))) void*)g,
        (__attribute__((address_space(3))) void*)l, 16, 0, 0);
}
__device__ __forceinline__ unsigned short f2bf(float x) {
    __hip_bfloat16 h = __float2bfloat16(x);
    return *reinterpret_cast<unsigned short*>(&h);
}
__device__ __forceinline__ float bf2f(unsigned short u) {
    __hip_bfloat16 h; *reinterpret_cast<unsigned short*>(&h) = u;
    return __bfloat162float(h);
}

// ---------------------------------------------------------------------------
// A: codebook -> bf16 hi/lo split + row norms (plain row-major; argmin kernel
// applies the LDS swizzle via pre-swizzled global source addresses).
__global__ __launch_bounds__(256)
void vq_prep_kernel(const float* __restrict__ cb, unsigned char* __restrict__ scratch) {
    unsigned short* cbh = (unsigned short*)(scratch + CBHI_OFF);
    unsigned short* cbl = (unsigned short*)(scratch + CBLO_OFF);
    float* cn = (float*)(scratch + CNORM_OFF);
    int t = threadIdx.x;
    int row = blockIdx.x * 16 + (t >> 4);   // grid 64
    int dq  = t & 15;
    const float* rp = cb + (size_t)row * DD + dq * 16;
    float nrm = 0.f;
    __attribute__((aligned(16))) unsigned short h[16];
    __attribute__((aligned(16))) unsigned short l[16];
#pragma unroll
    for (int i = 0; i < 4; ++i) {
        float4 v = *(const float4*)(rp + i * 4);
        float xs[4] = {v.x, v.y, v.z, v.w};
#pragma unroll
        for (int j = 0; j < 4; ++j) {
            float x = xs[j];
            unsigned short hi = f2bf(x);
            h[i*4+j] = hi;
            l[i*4+j] = f2bf(x - bf2f(hi));
            nrm = fmaf(x, x, nrm);
        }
    }
    *(uint4*)&cbh[row*DD + dq*16]     = *(uint4*)&h[0];
    *(uint4*)&cbh[row*DD + dq*16 + 8] = *(uint4*)&h[8];
    *(uint4*)&cbl[row*DD + dq*16]     = *(uint4*)&l[0];
    *(uint4*)&cbl[row*DD + dq*16 + 8] = *(uint4*)&l[8];
#pragma unroll
    for (int m = 1; m < 16; m <<= 1) nrm += __shfl_xor(nrm, m, 64);
    if (dq == 0) cn[row] = nrm;
}

// ---------------------------------------------------------------------------
// B: MFMA distance-argmin. 512 threads = 8 waves; 4 row-groups (16 rows each)
// x 2 k-half waves; 64 rows/block, grid 512 -> 2 blocks/CU (4 waves/SIMD).
// z A-fragments (hi/lo) register-resident; codebook double-buffered in LDS,
// one barrier per 32-k tile, prefetch issued before compute. Two alternating
// accumulators halve the dependent-MFMA chain depth.
__global__ __launch_bounds__(512, 4)
void vq_mfma_argmin_kernel(const float* __restrict__ z, unsigned char* __restrict__ scratch) {
    const unsigned char* cbh_b = scratch + CBHI_OFF;
    const unsigned char* cbl_b = scratch + CBLO_OFF;
    const float* cn_g = (const float*)(scratch + CNORM_OFF);
    float* rowrec = (float*)(scratch + ROWREC_OFF);

    __shared__ short cbuf[2][2][32 * 256];   // [buf][hi/lo][k][d] 64 KB, swizzled
    __shared__ float red[8][16][4];          // 2 KB

    const int t     = threadIdx.x;
    const int w     = t >> 6;
    const int lane  = t & 63;
    const int ln15  = lane & 15;
    const int lh    = lane >> 4;
    const int g     = w >> 1;        // row-group 0..3 (16 rows each)
    const int khalf = w & 1;         // which 16 of each 32-k tile

    const int n0  = blockIdx.x * 64;
    const int b   = n0 >> 10;
    const int hw0 = n0 & 1023;

    // staging lane constants (gload16: per-lane source, linear LDS dest)
    const int ksub  = lane >> 5;     // 0/1: which row of the lane-pair
    const int chunk = lane & 31;     // 16B chunk within the 512B row

    // read-side constants
    const int klr   = khalf * 16 + ln15;          // B-frag k row in tile
    const int rbase = klr * 256;                  // shorts
    const int rxor  = (klr & 7) << 3;             // swizzle (short units)

    // ---- prologue: stage tile 0, load z A-fragments (hi/lo) into registers
#pragma unroll
    for (int si = 0; si < 4; ++si) {
        int gi = w * 4 + si;
        int p  = gi >> 4, rp = gi & 15;
        int kl = rp * 2 + ksub;
        const unsigned char* src = (p ? cbl_b : cbh_b)
            + (size_t)kl * 512 + ((chunk ^ (kl & 7)) << 4);
        gload16(src, &cbuf[0][p][rp * 2 * 256]);
    }

    s16x8 ah[8], al[8];
    {
        const float* zp = z + (size_t)b * DD * HWD + hw0 + g * 16 + ln15;
#pragma unroll
        for (int ds = 0; ds < 8; ++ds) {
            const int d0 = ds * 32 + lh * 8;
#pragma unroll
            for (int j = 0; j < 8; ++j) {
                float x = zp[(size_t)(d0 + j) * HWD];
                unsigned short hi = f2bf(x);
                unsigned short lo = f2bf(x - bf2f(hi));
                ah[ds][j] = (short)hi;
                al[ds][j] = (short)lo;
            }
        }
    }
    __syncthreads();

    float v1[4], k1[4], v2[4], k2[4];
#pragma unroll
    for (int s = 0; s < 4; ++s) { v1[s] = 3e38f; v2[s] = 3e38f; k1[s] = 0.f; k2[s] = 0.f; }

    for (int kt = 0; kt < 32; ++kt) {
        const int cur = kt & 1;
        if (kt < 31) {                 // prefetch next tile into other buffer
            const int k0n = (kt + 1) * 32;
#pragma unroll
            for (int si = 0; si < 4; ++si) {
                int gi = w * 4 + si;
                int p  = gi >> 4, rp = gi & 15;
                int kl = rp * 2 + ksub;
                const unsigned char* src = (p ? cbl_b : cbh_b)
                    + (size_t)(k0n + kl) * 512 + ((chunk ^ (kl & 7)) << 4);
                gload16(src, &cbuf[cur ^ 1][p][rp * 2 * 256]);
            }
        }

        // hoist the epilogue's norm load above the MFMA phase
        const int kg = kt * 32 + khalf * 16 + ln15;
        const float cnv = cn_g[kg];
        const float kgf = (float)kg;

        f32x4 acc_a = {0.f, 0.f, 0.f, 0.f};
        f32x4 acc_b = {0.f, 0.f, 0.f, 0.f};
        const short* ch = &cbuf[cur][0][0];
        const short* cl = &cbuf[cur][1][0];
#pragma unroll
        for (int ds = 0; ds < 8; ds += 2) {
            const int ib0 = rbase + (((ds + 0) * 32 + lh * 8) ^ rxor);
            const int ib1 = rbase + (((ds + 1) * 32 + lh * 8) ^ rxor);
            s16x8 bh0 = *(const s16x8*)&ch[ib0];
            s16x8 bl0 = *(const s16x8*)&cl[ib0];
            s16x8 bh1 = *(const s16x8*)&ch[ib1];
            s16x8 bl1 = *(const s16x8*)&cl[ib1];
            acc_a = __builtin_amdgcn_mfma_f32_16x16x32_bf16(ah[ds + 0], bh0, acc_a, 0, 0, 0);
            acc_b = __builtin_amdgcn_mfma_f32_16x16x32_bf16(ah[ds + 1], bh1, acc_b, 0, 0, 0);
            acc_a = __builtin_amdgcn_mfma_f32_16x16x32_bf16(al[ds + 0], bh0, acc_a, 0, 0, 0);
            acc_b = __builtin_amdgcn_mfma_f32_16x16x32_bf16(al[ds + 1], bh1, acc_b, 0, 0, 0);
            acc_a = __builtin_amdgcn_mfma_f32_16x16x32_bf16(ah[ds + 0], bl0, acc_a, 0, 0, 0);
            acc_b = __builtin_amdgcn_mfma_f32_16x16x32_bf16(ah[ds + 1], bl1, acc_b, 0, 0, 0);
        }

        // top-2 update: per lane one col kg, 4 row-slots
        {
            f32x4 accs = acc_a + acc_b;
#pragma unroll
            for (int s = 0; s < 4; ++s) {
                float dist = fmaf(-2.f, accs[s], cnv);
                bool b1 = dist < v1[s];
                bool b2 = dist < v2[s];
                float nv2 = b1 ? v1[s] : (b2 ? dist : v2[s]);
                float nk2 = b1 ? k1[s] : (b2 ? kgf  : k2[s]);
                v2[s] = nv2; k2[s] = nk2;
                v1[s] = b1 ? dist : v1[s];
                k1[s] = b1 ? kgf  : k1[s];
            }
        }
        __syncthreads();   // buffer handoff; drains prefetch issued before compute
    }

    // ---- merge top-2 across the 16 cols held by ln15 lanes
#pragma unroll
    for (int m = 1; m < 16; m <<= 1) {
#pragma unroll
        for (int s = 0; s < 4; ++s) {
            float ov1 = __shfl_xor(v1[s], m, 64);
            float ok1 = __shfl_xor(k1[s], m, 64);
            float ov2 = __shfl_xor(v2[s], m, 64);
            float ok2 = __shfl_xor(k2[s], m, 64);
            bool alt = ov1 < v1[s];
            float nv1 = alt ? ov1 : v1[s];
            float nk1 = alt ? ok1 : k1[s];
            float cnd = alt ? v1[s] : ov1;
            float cndk = alt ? k1[s] : ok1;
            float oth = alt ? ov2 : v2[s];
            float othk = alt ? ok2 : k2[s];
            bool sec = oth < cnd;
            v1[s] = nv1; k1[s] = nk1;
            v2[s] = sec ? oth : cnd;
            k2[s] = sec ? othk : cndk;
        }
    }
    if (ln15 == 0) {
#pragma unroll
        for (int s = 0; s < 4; ++s) {
            int rl = lh * 4 + s;                // row-local within group (C-layout)
            red[w][rl][0] = v1[s]; red[w][rl][1] = k1[s];
            red[w][rl][2] = v2[s]; red[w][rl][3] = k2[s];
        }
    }
    __syncthreads();
    if (t < 64) {                               // merge the 2 k-half waves per group
        int gg = t >> 4, rl = t & 15;
        float a1 = red[gg*2][rl][0], ak1 = red[gg*2][rl][1];
        float a2 = red[gg*2][rl][2], ak2 = red[gg*2][rl][3];
        float b1v = red[gg*2+1][rl][0], bk1 = red[gg*2+1][rl][1];
        float b2v = red[gg*2+1][rl][2], bk2 = red[gg*2+1][rl][3];
        bool alt = b1v < a1;
        float nv1 = alt ? b1v : a1, nk1 = alt ? bk1 : ak1;
        float cnd = alt ? a1 : b1v, cndk = alt ? ak1 : bk1;
        float oth = alt ? b2v : a2, othk = alt ? bk2 : ak2;
        bool sec = oth < cnd;
        float4 rec;
        rec.x = nv1; rec.y = nk1;
        rec.z = sec ? oth : cnd; rec.w = sec ? othk : cndk;
        *(float4*)&rowrec[(size_t)(n0 + t) * 4] = rec;
    }
}

// ---------------------------------------------------------------------------
// R: ambiguous rows (approx gap <= TH) -> exact fp32 recheck of top-2 (first-min)
__global__ __launch_bounds__(256)
void vq_refine_kernel(const float* __restrict__ z, const float* __restrict__ cb,
                      const unsigned char* __restrict__ scratch, float* __restrict__ idx_out) {
    const float* rowrec = (const float*)(scratch + ROWREC_OFF);
    int n = blockIdx.x * 256 + threadIdx.x;       // grid 128
    int lane = threadIdx.x & 63;
    float4 rec = *(const float4*)&rowrec[(size_t)n * 4];
    bool need = (rec.z - rec.x) <= TH_REFINE;
    if (!need) idx_out[n] = rec.y;
    unsigned long long mask = __ballot(need);
    while (mask) {
        int li = __ffsll(mask) - 1;
        mask &= mask - 1;
        int nn  = __shfl(n, li);
        int kk1 = (int)__shfl(rec.y, li);
        int kk2 = (int)__shfl(rec.w, li);
        int bb = nn >> 10, hw = nn & 1023;
        const float* zp  = z  + (size_t)bb * DD * HWD + hw;
        const float* c1p = cb + (size_t)kk1 * DD;
        const float* c2p = cb + (size_t)kk2 * DD;
        float s1 = 0.f, s2 = 0.f;
#pragma unroll
        for (int j = 0; j < 4; ++j) {
            int d = lane + 64 * j;
            float zv = zp[(size_t)d * HWD];
            float t1 = zv - c1p[d]; s1 = fmaf(t1, t1, s1);
            float t2 = zv - c2p[d]; s2 = fmaf(t2, t2, s2);
        }
#pragma unroll
        for (int m = 32; m >= 1; m >>= 1) { s1 += __shfl_xor(s1, m, 64); s2 += __shfl_xor(s2, m, 64); }
        int choice = (s1 < s2) ? kk1 : ((s2 < s1) ? kk2 : (kk1 < kk2 ? kk1 : kk2));
        if (lane == 0) idx_out[nn] = (float)choice;
    }
}

// ---------------------------------------------------------------------------
// C: tiled gather (LDS row cache, coalesced writes) + commitment loss
__global__ __launch_bounds__(256)
void vq_gather_loss_kernel(const float* __restrict__ z, const float* __restrict__ cb,
                           float* __restrict__ out) {
    const float* idxf = out + IDX_OFF;
    float* lossp = out + LOSS_OFF;
    __shared__ float crow[64][257];
    __shared__ int kidx[64];
    __shared__ float bl[4];
    int t = threadIdx.x;
    int w = t >> 6, lane = t & 63;
    int n0 = blockIdx.x * 64;                      // grid 512
    int b = n0 >> 10, hw0 = n0 & 1023;
    if (t < 64) kidx[t] = (int)idxf[n0 + t];
    __syncthreads();
    for (int i = 0; i < 16; ++i) {                 // stage 64 code rows (coalesced 1KB/wave)
        int r = w * 16 + i;
        int k = kidx[r];
        float4 v = *(const float4*)(cb + (size_t)k * DD + lane * 4);
        crow[r][lane * 4 + 0] = v.x; crow[r][lane * 4 + 1] = v.y;
        crow[r][lane * 4 + 2] = v.z; crow[r][lane * 4 + 3] = v.w;
    }
    __syncthreads();
    float local = 0.f;
    const int zph = t >> 6, hwl = t & 63;
    for (int dd = 0; dd < 64; ++dd) {
        int d = dd * 4 + zph;
        float val = crow[hwl][d];                  // banks (hwl+d)%32: 2-way, free
        size_t o = (size_t)b * (DD * HWD) + (size_t)d * HWD + hw0 + hwl;
        float zv = z[o];
        out[o] = val;
        float df = zv - val;
        local = fmaf(df, df, local);
    }
#pragma unroll
    for (int m = 32; m >= 1; m >>= 1) local += __shfl_xor(local, m, 64);
    if (lane == 0) bl[w] = local;
    __syncthreads();
    if (t == 0) {
        float s = bl[0] + bl[1] + bl[2] + bl[3];
        atomicAdd(lossp, s * (0.25f / (float)ZQ_SIZE));
    }
}

// ---------------------------------------------------------------------------
extern "C" void kernel_launch(void* const* d_in, const int* in_sizes, int n_in,
                              void* d_out, int out_size, void* d_ws, size_t ws_size,
                              hipStream_t stream) {
    const float* z  = (const float*)d_in[0];
    const float* cb = (const float*)d_in[1];
    float* out = (float*)d_out;
    unsigned char* scratch = (unsigned char*)d_out;   // z_q region, overwritten by gather

    hipMemsetAsync((void*)(out + LOSS_OFF), 0, sizeof(float), stream);

    vq_prep_kernel<<<64, 256, 0, stream>>>(cb, scratch);
    vq_mfma_argmin_kernel<<<512, 512, 0, stream>>>(z, scratch);
    vq_refine_kernel<<<128, 256, 0, stream>>>(z, cb, scratch, out + IDX_OFF);
    vq_gather_loss_kernel<<<512, 256, 0, stream>>>(z, cb, out);
}